// Round 3
// baseline (1605.708 us; speedup 1.0000x reference)
//
#include <hip/hip_runtime.h>

#define ALPHA 0.2f
__device__ __forceinline__ float lrelu_f(float x){ return x>0.f ? x : ALPHA*x; }
__device__ __forceinline__ float4 zero4(){ float4 z; z.x=z.y=z.z=z.w=0.f; return z; }

// XCD-chunk swizzle: consecutive physical blocks land on the same XCD's contiguous
// logical chunk. Bijective iff grid%8==0; identity fallback otherwise.
__device__ __forceinline__ int swz_bid(){
  int nb = gridDim.x, b = blockIdx.x;
  return ((nb & 7)==0) ? ((b & 7)*(nb>>3) + (b>>3)) : b;
}

// ============ Encoder: 3x3 s2 SAME conv (pad lo=0,hi=1), TO chans x TX pixels per thread ====
template<int H,int W,int CIN,int COUT,int TO,int TX,bool LRELU>
__global__ __launch_bounds__(256) void conv3x3_s2_k(const float* __restrict__ in,
    const float* __restrict__ w, const float* __restrict__ bias, float* __restrict__ out,
    int total){
  constexpr int Ho=H/2, Wo=W/2, OB=COUT/TO, XB=Wo/TX;
  int t = swz_bid()*256 + threadIdx.x;
  if (t >= total) return;
  int ob = t % OB; int p = t/OB;
  int xb = p % XB; p /= XB;
  int y  = p % Ho; int n = p/Ho;
  int x0 = xb*TX;

  float acc[TX][TO];
  #pragma unroll
  for (int j4=0;j4<TO/4;j4++){
    float4 bv = *(const float4*)(bias + ob*TO + j4*4);
    #pragma unroll
    for (int px=0;px<TX;px++){
      acc[px][j4*4+0]=bv.x; acc[px][j4*4+1]=bv.y;
      acc[px][j4*4+2]=bv.z; acc[px][j4*4+3]=bv.w;
    }
  }

  #pragma unroll
  for (int ky=0;ky<3;ky++){
    int iy = 2*y + ky;
    if (iy >= H) continue;
    const float* row = in + ((size_t)n*H + iy)*(size_t)(W*CIN);
    #pragma unroll
    for (int kx=0;kx<3;kx++){
      const float* wp = w + ((ky*3+kx)*CIN)*COUT + ob*TO;
      const float* ipx[TX]; bool okx[TX];
      #pragma unroll
      for (int px=0;px<TX;px++){
        int ix = 2*(x0+px)+kx;
        okx[px] = (ix < W);
        ipx[px] = row + (size_t)(okx[px] ? ix : (W-1))*CIN;
      }
      if constexpr (CIN==3){
        #pragma unroll
        for (int ci=0;ci<3;ci++){
          float4 wv[TO/4];
          #pragma unroll
          for (int j4=0;j4<TO/4;j4++) wv[j4] = *(const float4*)(wp + ci*COUT + j4*4);
          #pragma unroll
          for (int px=0;px<TX;px++){
            float v = okx[px] ? ipx[px][ci] : 0.f;
            #pragma unroll
            for (int j4=0;j4<TO/4;j4++){
              acc[px][j4*4+0] += v*wv[j4].x; acc[px][j4*4+1] += v*wv[j4].y;
              acc[px][j4*4+2] += v*wv[j4].z; acc[px][j4*4+3] += v*wv[j4].w;
            }
          }
        }
      } else {
        for (int c=0;c<CIN;c+=4){
          float4 wv[4][TO/4];
          #pragma unroll
          for (int ci=0;ci<4;ci++)
            #pragma unroll
            for (int j4=0;j4<TO/4;j4++)
              wv[ci][j4] = *(const float4*)(wp + (c+ci)*COUT + j4*4);
          #pragma unroll
          for (int px=0;px<TX;px++){
            float4 vv = *(const float4*)(ipx[px]+c);
            if (!okx[px]) vv = zero4();
            float vc[4] = {vv.x, vv.y, vv.z, vv.w};
            #pragma unroll
            for (int ci=0;ci<4;ci++)
              #pragma unroll
              for (int j4=0;j4<TO/4;j4++){
                acc[px][j4*4+0] += vc[ci]*wv[ci][j4].x;
                acc[px][j4*4+1] += vc[ci]*wv[ci][j4].y;
                acc[px][j4*4+2] += vc[ci]*wv[ci][j4].z;
                acc[px][j4*4+3] += vc[ci]*wv[ci][j4].w;
              }
          }
        }
      }
    }
  }
  #pragma unroll
  for (int px=0;px<TX;px++){
    float* op = out + ((size_t)((n*Ho+y)*Wo + x0+px))*COUT + ob*TO;
    #pragma unroll
    for (int j4=0;j4<TO/4;j4++){
      float4 r;
      r.x = LRELU?lrelu_f(acc[px][j4*4+0]):acc[px][j4*4+0];
      r.y = LRELU?lrelu_f(acc[px][j4*4+1]):acc[px][j4*4+1];
      r.z = LRELU?lrelu_f(acc[px][j4*4+2]):acc[px][j4*4+2];
      r.w = LRELU?lrelu_f(acc[px][j4*4+3]):acc[px][j4*4+3];
      *(float4*)(op+j4*4) = r;
    }
  }
}

// ============ Fused enc4 (1x1 conv 64->32) + vector-quantize ============
template<int CIN,int D,int K>
__global__ __launch_bounds__(256) void enc4_vq_k(const float* __restrict__ in,
    const float* __restrict__ w, const float* __restrict__ bias,
    const float* __restrict__ cb, float* __restrict__ q, int npix){
  int i = blockIdx.x*256 + threadIdx.x;
  if (i >= npix) return;
  const float* ip = in + (size_t)i*CIN;
  float z[D];
  #pragma unroll
  for (int d=0; d<D; d++) z[d] = bias[d];
  for (int c=0; c<CIN; c+=4){
    float4 v = *(const float4*)(ip + c);
    #pragma unroll
    for (int d=0; d<D; d++){
      z[d] += v.x * w[(c+0)*D + d];
      z[d] += v.y * w[(c+1)*D + d];
      z[d] += v.z * w[(c+2)*D + d];
      z[d] += v.w * w[(c+3)*D + d];
    }
  }
  float z2 = 0.f;
  #pragma unroll
  for (int d=0; d<D; d++) z2 += z[d]*z[d];
  float best = 3.4e38f; int bi = 0;
  for (int k=0; k<K; k++){
    float e2 = 0.f, dot = 0.f;
    #pragma unroll
    for (int d=0; d<D; d++){
      float cv = cb[d*K + k];
      e2  += cv*cv;
      dot += z[d]*cv;
    }
    float dist = z2 + e2 - 2.f*dot;
    if (dist < best){ best = dist; bi = k; }   // strict < == first-min (jnp.argmin)
  }
  float* qp = q + (size_t)i*D;
  #pragma unroll
  for (int d=0; d<D; d++) qp[d] = cb[d*K + bi];
}

// ============ Parity-fused decoder conv_transpose 3x3 s2 SAME (JAX, unflipped) ============
// One thread: 2x2 output parities x TX input-cols x TO channels. ob is block-level; the
// block's 9*CIN*TO weight slice is staged in LDS and read back with broadcast ds_read_b128.
// TO=4/TX=4: halves weight ds_reads per FMA vs TO=8/TX=2 (same 576 FMA per c-chunk/thread).
template<int KY0,int NKY,int CIN,int TO,int TX>
__device__ __forceinline__ void dtap_row(const float* __restrict__ row,
    const float* __restrict__ wl, int x0, float (&acc)[2][2*TX][TO]){
  for (int c=0;c<CIN;c+=4){
    float4 v[TX+1];                      // input cols x0-1 .. x0+TX-1 (loaded once)
    #pragma unroll
    for (int j=0;j<=TX;j++){
      int xi = x0 - 1 + j;
      bool ok = (xi >= 0);
      float4 t4 = *(const float4*)(row + (size_t)(ok ? xi : 0)*CIN + c);
      if (!ok) t4 = zero4();
      v[j] = t4;
    }
    #pragma unroll
    for (int kk=0;kk<NKY;kk++){
      const int ky = KY0 + kk;
      const int py = (ky==1) ? 1 : 0;
      #pragma unroll
      for (int kx=0;kx<3;kx++){
        const int pxp = (kx==1) ? 1 : 0;
        const float* wp = wl + ((ky*3+kx)*CIN + c)*TO;   // LDS, wave-uniform
        float4 wv[4][TO/4];
        #pragma unroll
        for (int ci=0;ci<4;ci++)
          #pragma unroll
          for (int j4=0;j4<TO/4;j4++)
            wv[ci][j4] = *(const float4*)(wp + ci*TO + j4*4);
        #pragma unroll
        for (int px=0;px<TX;px++){
          const int jj = (kx==0) ? px : (px+1);   // dx=-1 -> col x0+px-1; dx=0 -> col x0+px
          float vc[4] = {v[jj].x, v[jj].y, v[jj].z, v[jj].w};
          #pragma unroll
          for (int ci=0;ci<4;ci++)
            #pragma unroll
            for (int j4=0;j4<TO/4;j4++){
              acc[py][2*px+pxp][j4*4+0] += vc[ci]*wv[ci][j4].x;
              acc[py][2*px+pxp][j4*4+1] += vc[ci]*wv[ci][j4].y;
              acc[py][2*px+pxp][j4*4+2] += vc[ci]*wv[ci][j4].z;
              acc[py][2*px+pxp][j4*4+3] += vc[ci]*wv[ci][j4].w;
            }
        }
      }
    }
  }
}

template<int H,int W,int CIN,int COUT,int TO,int TX,bool LRELU>
__global__ __launch_bounds__(256) void deconv3x3_s2_fused_k(const float* __restrict__ in,
    const float* __restrict__ w, const float* __restrict__ bias, float* __restrict__ out){
  constexpr int Ho=2*H, Wo=2*W, OB=COUT/TO, XB2=W/TX, TYR=256/XB2, YG=H/TYR;
  constexpr int WN = 9*CIN*TO;          // floats in this block's weight slice
  static_assert(256 % XB2 == 0 && H % TYR == 0, "geometry");
  __shared__ float wlds[WN];

  int lb = swz_bid();
  int ob = lb % OB; int g = lb / OB;
  int yg = g % YG;  int n  = g / YG;
  int xb = threadIdx.x % XB2, yr = threadIdx.x / XB2;
  int yy = yg*TYR + yr, x0 = xb*TX;

  // stage weight slice: w[(tap*CIN+c)*COUT + ob*TO + j] -> wlds[(tap*CIN+c)*TO + j]
  {
    const int base = ob*TO;
    for (int i = threadIdx.x; i < WN/4; i += 256){
      int j4 = i % (TO/4); int rest = i / (TO/4);          // rest = tap*CIN + c
      ((float4*)wlds)[i] = *(const float4*)(w + (size_t)rest*COUT + base + j4*4);
    }
  }
  __syncthreads();

  float acc[2][2*TX][TO];
  #pragma unroll
  for (int j4=0;j4<TO/4;j4++){
    float4 bv = *(const float4*)(bias + ob*TO + j4*4);
    #pragma unroll
    for (int py=0;py<2;py++)
      #pragma unroll
      for (int q=0;q<2*TX;q++){
        acc[py][q][j4*4+0]=bv.x; acc[py][q][j4*4+1]=bv.y;
        acc[py][q][j4*4+2]=bv.z; acc[py][q][j4*4+3]=bv.w;
      }
  }

  const float* base = in + (size_t)n*H*(size_t)(W*CIN);
  if (yy > 0)
    dtap_row<0,1,CIN,TO,TX>(base + (size_t)(yy-1)*(size_t)(W*CIN), wlds, x0, acc);
  dtap_row<1,2,CIN,TO,TX>(base + (size_t)yy*(size_t)(W*CIN), wlds, x0, acc);

  #pragma unroll
  for (int py=0;py<2;py++){
    int yo = 2*yy + py;
    #pragma unroll
    for (int q=0;q<2*TX;q++){
      int xo = 2*x0 + q;
      float* op = out + ((size_t)(n*Ho+yo)*(size_t)Wo + xo)*COUT + ob*TO;
      #pragma unroll
      for (int j4=0;j4<TO/4;j4++){
        float4 r;
        r.x = LRELU?lrelu_f(acc[py][q][j4*4+0]):acc[py][q][j4*4+0];
        r.y = LRELU?lrelu_f(acc[py][q][j4*4+1]):acc[py][q][j4*4+1];
        r.z = LRELU?lrelu_f(acc[py][q][j4*4+2]):acc[py][q][j4*4+2];
        r.w = LRELU?lrelu_f(acc[py][q][j4*4+3]):acc[py][q][j4*4+3];
        *(float4*)(op+j4*4) = r;
      }
    }
  }
}

// ============ dec4: s1 deconv == 3x3 pad-1 conv, Cout=1 — LDS-tiled ============
// Block: 8 output rows x 128 cols; stages (10 x 130 x 8ch) input tile per c-chunk.
// Bijective col-XOR swizzle (col ^ ((col>>2)&7)) spreads the TX=4-col lane stride
// across all 8 bank-groups -> conflict-free ds_read_b128.
template<int H,int W,int CIN>
__global__ __launch_bounds__(256) void dec4_tiled_k(const float* __restrict__ in,
    const float* __restrict__ w, const float* __restrict__ bias, float* __restrict__ out){
  constexpr int TX=4, WB=128, TYB=8, GX=W/WB, GY=H/TYB, COLS=WB+2, ROWS=TYB+2;
  constexpr int NPIX = ROWS*COLS;                 // 1300 float4 slots per plane
  __shared__ float4 tile[2*NPIX];                 // plane0: ch c0..c0+3, plane1: c0+4..c0+7
  __shared__ float4 wsh[(9*CIN)/4];               // full 3x3xCIN weight (1.15 KB)

  int lb = swz_bid();
  int gx = lb % GX; int rest = lb / GX;
  int yg = rest % GY; int n = rest / GY;
  int xb = threadIdx.x & 31, yr = threadIdx.x >> 5;
  int y0 = yg*TYB, xbase = gx*WB;

  if (threadIdx.x < (9*CIN)/4) wsh[threadIdx.x] = ((const float4*)w)[threadIdx.x];

  float b0 = bias[0];
  float acc[TX];
  #pragma unroll
  for (int px=0;px<TX;px++) acc[px] = b0;

  for (int cc=0; cc<CIN/8; ++cc){
    __syncthreads();                               // prev reads done before overwrite
    for (int i = threadIdx.x; i < NPIX; i += 256){
      int row = i / COLS, col = i % COLS;
      int grow = y0 - 1 + row, gcol = xbase - 1 + col;
      float4 a0 = zero4(), a1 = zero4();
      if ((unsigned)grow < (unsigned)H && (unsigned)gcol < (unsigned)W){
        const float* gp = in + (((size_t)n*H + grow)*(size_t)W + gcol)*CIN + cc*8;
        a0 = *(const float4*)gp; a1 = *(const float4*)(gp + 4);
      }
      int p = row*COLS + (col ^ ((col>>2)&7));
      tile[p] = a0; tile[NPIX + p] = a1;
    }
    __syncthreads();

    #pragma unroll
    for (int ky=0;ky<3;ky++){
      int rowb = (yr + ky)*COLS;
      float4 w0[3], w1[3];
      #pragma unroll
      for (int kx=0;kx<3;kx++){
        int tf = (ky*3+kx)*(CIN/4) + cc*2;
        w0[kx] = wsh[tf]; w1[kx] = wsh[tf+1];
      }
      #pragma unroll
      for (int j=0;j<TX+2;j++){
        int col = 4*xb + j;
        int p = rowb + (col ^ ((col>>2)&7));
        float4 a0 = tile[p], a1 = tile[NPIX + p];
        #pragma unroll
        for (int kx=0;kx<3;kx++){
          int px = j - kx;
          if (px >= 0 && px < TX){
            acc[px] += a0.x*w0[kx].x + a0.y*w0[kx].y + a0.z*w0[kx].z + a0.w*w0[kx].w
                     + a1.x*w1[kx].x + a1.y*w1[kx].y + a1.z*w1[kx].z + a1.w*w1[kx].w;
          }
        }
      }
    }
  }

  int y = y0 + yr;
  float* op = out + ((size_t)n*H + y)*(size_t)W + xbase + 4*xb;
  float4 r; r.x=acc[0]; r.y=acc[1]; r.z=acc[2]; r.w=acc[3];
  *(float4*)op = r;
}

extern "C" void kernel_launch(void* const* d_in, const int* in_sizes, int n_in,
                              void* d_out, int out_size, void* d_ws, size_t ws_size,
                              hipStream_t stream) {
  const float* x   = (const float*)d_in[0];
  const float* e1w = (const float*)d_in[1];  const float* e1b = (const float*)d_in[2];
  const float* e2w = (const float*)d_in[3];  const float* e2b = (const float*)d_in[4];
  const float* e3w = (const float*)d_in[5];  const float* e3b = (const float*)d_in[6];
  const float* e4w = (const float*)d_in[7];  const float* e4b = (const float*)d_in[8];
  const float* cb  = (const float*)d_in[9];
  const float* d1w = (const float*)d_in[10]; const float* d1b = (const float*)d_in[11];
  const float* d2w = (const float*)d_in[12]; const float* d2b = (const float*)d_in[13];
  const float* d3w = (const float*)d_in[14]; const float* d3b = (const float*)d_in[15];
  const float* d4w = (const float*)d_in[16]; const float* d4b = (const float*)d_in[17];
  float* out = (float*)d_out;

  // Per-image ping-pong: A = max(h1,h3,d1,d3) = 8 MiB/img; B = max(h2,q,d2) = 4 MiB/img.
  const size_t MiB = 1ull << 20;
  int Bc = 32;
  while (Bc > 1 && (size_t)Bc * 12 * MiB > ws_size) Bc >>= 1;

  char* wsb = (char*)d_ws;
  float* A  = (float*)wsb;                              // Bc * 8 MiB
  float* Bf = (float*)(wsb + (size_t)Bc * 8 * MiB);     // Bc * 4 MiB

  for (int n0 = 0; n0 < 32; n0 += Bc) {
    const float* xc = x   + (size_t)n0 * 256*256*3;
    float*      oc  = out + (size_t)n0 * 256*256;

    // enc1: [Bc,256,256,3] -> [Bc,128,128,32]; TO=8(OB=4), TX=2(XB=64)
    int t1 = Bc*128*64*4;
    conv3x3_s2_k<256,256,3,32,8,2,true><<<t1/256,256,0,stream>>>(xc, e1w, e1b, A, t1);
    // enc2: -> [Bc,64,64,64]
    int t2 = Bc*64*32*8;
    conv3x3_s2_k<128,128,32,64,8,2,true><<<t2/256,256,0,stream>>>(A, e2w, e2b, Bf, t2);
    // enc3: -> [Bc,32,32,64]
    int t3 = Bc*32*16*8;
    conv3x3_s2_k<64,64,64,64,8,2,true><<<t3/256,256,0,stream>>>(Bf, e3w, e3b, A, t3);
    // enc4 (1x1, 64->32) + VQ: -> q [Bc,32,32,32]
    int npix = Bc*32*32;
    enc4_vq_k<64,32,64><<<npix/256,256,0,stream>>>(A, e4w, e4b, cb, Bf, npix);
    // dec1: [Bc,32,32,32] -> [Bc,64,64,64]; TO=4(OB=16), TX=4: XB2=8,TYR=32,YG=1 -> Bc*16
    deconv3x3_s2_fused_k<32,32,32,64,4,4,true><<<Bc*16,256,0,stream>>>(Bf, d1w, d1b, A);
    // dec2: -> [Bc,128,128,64]; TO=4(OB=16), TX=4: XB2=16,TYR=16,YG=4 -> Bc*64
    deconv3x3_s2_fused_k<64,64,64,64,4,4,true><<<Bc*64,256,0,stream>>>(A, d2w, d2b, Bf);
    // dec3: -> [Bc,256,256,32]; TO=4(OB=8), TX=4: XB2=32,TYR=8,YG=16 -> Bc*128
    deconv3x3_s2_fused_k<128,128,64,32,4,4,true><<<Bc*128,256,0,stream>>>(Bf, d3w, d3b, A);
    // dec4: -> [Bc,256,256,1]; LDS-tiled, grid = Bc*GX*GY = Bc*64
    dec4_tiled_k<256,256,32><<<Bc*64,256,0,stream>>>(A, d4w, d4b, oc);
  }
}

// Round 4
// 1376.774 us; speedup vs baseline: 1.1663x; 1.1663x over previous
//
#include <hip/hip_runtime.h>

#define ALPHA 0.2f
__device__ __forceinline__ float lrelu_f(float x){ return x>0.f ? x : ALPHA*x; }
__device__ __forceinline__ float4 zero4(){ float4 z; z.x=z.y=z.z=z.w=0.f; return z; }

// XCD-chunk swizzle: consecutive physical blocks land on the same XCD's contiguous
// logical chunk. Bijective iff grid%8==0; identity fallback otherwise.
__device__ __forceinline__ int swz_bid(){
  int nb = gridDim.x, b = blockIdx.x;
  return ((nb & 7)==0) ? ((b & 7)*(nb>>3) + (b>>3)) : b;
}

// ============ Encoder: 3x3 s2 SAME conv (pad lo=0,hi=1), TO chans x TX pixels per thread ====
template<int H,int W,int CIN,int COUT,int TO,int TX,bool LRELU>
__global__ __launch_bounds__(256) void conv3x3_s2_k(const float* __restrict__ in,
    const float* __restrict__ w, const float* __restrict__ bias, float* __restrict__ out,
    int total){
  constexpr int Ho=H/2, Wo=W/2, OB=COUT/TO, XB=Wo/TX;
  int t = swz_bid()*256 + threadIdx.x;
  if (t >= total) return;
  int ob = t % OB; int p = t/OB;
  int xb = p % XB; p /= XB;
  int y  = p % Ho; int n = p/Ho;
  int x0 = xb*TX;

  float acc[TX][TO];
  #pragma unroll
  for (int j4=0;j4<TO/4;j4++){
    float4 bv = *(const float4*)(bias + ob*TO + j4*4);
    #pragma unroll
    for (int px=0;px<TX;px++){
      acc[px][j4*4+0]=bv.x; acc[px][j4*4+1]=bv.y;
      acc[px][j4*4+2]=bv.z; acc[px][j4*4+3]=bv.w;
    }
  }

  #pragma unroll
  for (int ky=0;ky<3;ky++){
    int iy = 2*y + ky;
    if (iy >= H) continue;
    const float* row = in + ((size_t)n*H + iy)*(size_t)(W*CIN);
    #pragma unroll
    for (int kx=0;kx<3;kx++){
      const float* wp = w + ((ky*3+kx)*CIN)*COUT + ob*TO;
      const float* ipx[TX]; bool okx[TX];
      #pragma unroll
      for (int px=0;px<TX;px++){
        int ix = 2*(x0+px)+kx;
        okx[px] = (ix < W);
        ipx[px] = row + (size_t)(okx[px] ? ix : (W-1))*CIN;
      }
      if constexpr (CIN==3){
        #pragma unroll
        for (int ci=0;ci<3;ci++){
          float4 wv[TO/4];
          #pragma unroll
          for (int j4=0;j4<TO/4;j4++) wv[j4] = *(const float4*)(wp + ci*COUT + j4*4);
          #pragma unroll
          for (int px=0;px<TX;px++){
            float v = okx[px] ? ipx[px][ci] : 0.f;
            #pragma unroll
            for (int j4=0;j4<TO/4;j4++){
              acc[px][j4*4+0] += v*wv[j4].x; acc[px][j4*4+1] += v*wv[j4].y;
              acc[px][j4*4+2] += v*wv[j4].z; acc[px][j4*4+3] += v*wv[j4].w;
            }
          }
        }
      } else {
        for (int c=0;c<CIN;c+=4){
          float4 wv[4][TO/4];
          #pragma unroll
          for (int ci=0;ci<4;ci++)
            #pragma unroll
            for (int j4=0;j4<TO/4;j4++)
              wv[ci][j4] = *(const float4*)(wp + (c+ci)*COUT + j4*4);
          #pragma unroll
          for (int px=0;px<TX;px++){
            float4 vv = *(const float4*)(ipx[px]+c);
            if (!okx[px]) vv = zero4();
            float vc[4] = {vv.x, vv.y, vv.z, vv.w};
            #pragma unroll
            for (int ci=0;ci<4;ci++)
              #pragma unroll
              for (int j4=0;j4<TO/4;j4++){
                acc[px][j4*4+0] += vc[ci]*wv[ci][j4].x;
                acc[px][j4*4+1] += vc[ci]*wv[ci][j4].y;
                acc[px][j4*4+2] += vc[ci]*wv[ci][j4].z;
                acc[px][j4*4+3] += vc[ci]*wv[ci][j4].w;
              }
          }
        }
      }
    }
  }
  #pragma unroll
  for (int px=0;px<TX;px++){
    float* op = out + ((size_t)((n*Ho+y)*Wo + x0+px))*COUT + ob*TO;
    #pragma unroll
    for (int j4=0;j4<TO/4;j4++){
      float4 r;
      r.x = LRELU?lrelu_f(acc[px][j4*4+0]):acc[px][j4*4+0];
      r.y = LRELU?lrelu_f(acc[px][j4*4+1]):acc[px][j4*4+1];
      r.z = LRELU?lrelu_f(acc[px][j4*4+2]):acc[px][j4*4+2];
      r.w = LRELU?lrelu_f(acc[px][j4*4+3]):acc[px][j4*4+3];
      *(float4*)(op+j4*4) = r;
    }
  }
}

// ============ Fused enc4 (1x1 conv 64->32) + vector-quantize ============
template<int CIN,int D,int K>
__global__ __launch_bounds__(256) void enc4_vq_k(const float* __restrict__ in,
    const float* __restrict__ w, const float* __restrict__ bias,
    const float* __restrict__ cb, float* __restrict__ q, int npix){
  int i = blockIdx.x*256 + threadIdx.x;
  if (i >= npix) return;
  const float* ip = in + (size_t)i*CIN;
  float z[D];
  #pragma unroll
  for (int d=0; d<D; d++) z[d] = bias[d];
  for (int c=0; c<CIN; c+=4){
    float4 v = *(const float4*)(ip + c);
    #pragma unroll
    for (int d=0; d<D; d++){
      z[d] += v.x * w[(c+0)*D + d];
      z[d] += v.y * w[(c+1)*D + d];
      z[d] += v.z * w[(c+2)*D + d];
      z[d] += v.w * w[(c+3)*D + d];
    }
  }
  float z2 = 0.f;
  #pragma unroll
  for (int d=0; d<D; d++) z2 += z[d]*z[d];
  float best = 3.4e38f; int bi = 0;
  for (int k=0; k<K; k++){
    float e2 = 0.f, dot = 0.f;
    #pragma unroll
    for (int d=0; d<D; d++){
      float cv = cb[d*K + k];
      e2  += cv*cv;
      dot += z[d]*cv;
    }
    float dist = z2 + e2 - 2.f*dot;
    if (dist < best){ best = dist; bi = k; }   // strict < == first-min (jnp.argmin)
  }
  float* qp = q + (size_t)i*D;
  #pragma unroll
  for (int d=0; d<D; d++) qp[d] = cb[d*K + bi];
}

// ============ Parity-fused decoder conv_transpose 3x3 s2 SAME (JAX, unflipped) ============
// One thread: 2x2 output parities x TX input-cols x TO channels. ob block-level; weights
// staged in LDS (broadcast ds_read_b128). MERGED c-loop: both input rows' loads (6 float4)
// issue back-to-back per c-chunk -> 2x memory-level parallelism vs per-row passes.
template<int H,int W,int CIN,int COUT,int TO,int TX,bool LRELU>
__global__ __launch_bounds__(256) void deconv3x3_s2_fused_k(const float* __restrict__ in,
    const float* __restrict__ w, const float* __restrict__ bias, float* __restrict__ out){
  constexpr int Ho=2*H, Wo=2*W, OB=COUT/TO, XB2=W/TX, TYR=256/XB2, YG=H/TYR;
  constexpr int WN = 9*CIN*TO;          // floats in this block's weight slice
  static_assert(256 % XB2 == 0 && H % TYR == 0, "geometry");
  __shared__ float wlds[WN];

  int lb = swz_bid();
  int ob = lb % OB; int g = lb / OB;
  int yg = g % YG;  int n  = g / YG;
  int xb = threadIdx.x % XB2, yr = threadIdx.x / XB2;
  int yy = yg*TYR + yr, x0 = xb*TX;

  // stage weight slice: w[(tap*CIN+c)*COUT + ob*TO + j] -> wlds[(tap*CIN+c)*TO + j]
  {
    const int base = ob*TO;
    for (int i = threadIdx.x; i < WN/4; i += 256){
      int j4 = i % (TO/4); int rest = i / (TO/4);          // rest = tap*CIN + c
      ((float4*)wlds)[i] = *(const float4*)(w + (size_t)rest*COUT + base + j4*4);
    }
  }
  __syncthreads();

  float acc[2][2*TX][TO];
  #pragma unroll
  for (int j4=0;j4<TO/4;j4++){
    float4 bv = *(const float4*)(bias + ob*TO + j4*4);
    #pragma unroll
    for (int py=0;py<2;py++)
      #pragma unroll
      for (int q=0;q<2*TX;q++){
        acc[py][q][j4*4+0]=bv.x; acc[py][q][j4*4+1]=bv.y;
        acc[py][q][j4*4+2]=bv.z; acc[py][q][j4*4+3]=bv.w;
      }
  }

  const float* base = in + (size_t)n*H*(size_t)(W*CIN);
  const bool has0 = (yy > 0);
  const float* r0 = base + (size_t)(has0 ? yy-1 : 0)*(size_t)(W*CIN);  // ky=0 row (dy=-1)
  const float* r1 = base + (size_t)yy*(size_t)(W*CIN);                 // ky=1,2 rows (dy=0)

  for (int c=0;c<CIN;c+=4){
    // ---- issue all 6 loads for this c-chunk back-to-back ----
    float4 v0[TX+1], v1[TX+1];
    #pragma unroll
    for (int j=0;j<=TX;j++){
      int xi = x0 - 1 + j;
      bool ok = (xi >= 0);
      size_t off = (size_t)(ok ? xi : 0)*CIN + c;
      float4 a1 = *(const float4*)(r1 + off);
      float4 a0 = (has0) ? *(const float4*)(r0 + off) : zero4();
      if (!ok){ a1 = zero4(); a0 = zero4(); }
      v1[j] = a1; v0[j] = a0;
    }
    // ---- 9 taps ----
    #pragma unroll
    for (int ky=0;ky<3;ky++){
      const int py = (ky==1) ? 1 : 0;
      #pragma unroll
      for (int kx=0;kx<3;kx++){
        const int pxp = (kx==1) ? 1 : 0;
        const float* wp = wlds + ((ky*3+kx)*CIN + c)*TO;   // LDS, wave-uniform
        float4 wv[4][TO/4];
        #pragma unroll
        for (int ci=0;ci<4;ci++)
          #pragma unroll
          for (int j4=0;j4<TO/4;j4++)
            wv[ci][j4] = *(const float4*)(wp + ci*TO + j4*4);
        #pragma unroll
        for (int px=0;px<TX;px++){
          const int jj = (kx==0) ? px : (px+1);   // dx=-1 -> col x0+px-1; dx=0 -> col x0+px
          float4 vv = (ky==0) ? v0[jj] : v1[jj];
          float vc[4] = {vv.x, vv.y, vv.z, vv.w};
          #pragma unroll
          for (int ci=0;ci<4;ci++)
            #pragma unroll
            for (int j4=0;j4<TO/4;j4++){
              acc[py][2*px+pxp][j4*4+0] += vc[ci]*wv[ci][j4].x;
              acc[py][2*px+pxp][j4*4+1] += vc[ci]*wv[ci][j4].y;
              acc[py][2*px+pxp][j4*4+2] += vc[ci]*wv[ci][j4].z;
              acc[py][2*px+pxp][j4*4+3] += vc[ci]*wv[ci][j4].w;
            }
        }
      }
    }
  }

  #pragma unroll
  for (int py=0;py<2;py++){
    int yo = 2*yy + py;
    #pragma unroll
    for (int q=0;q<2*TX;q++){
      int xo = 2*x0 + q;
      float* op = out + ((size_t)(n*Ho+yo)*(size_t)Wo + xo)*COUT + ob*TO;
      #pragma unroll
      for (int j4=0;j4<TO/4;j4++){
        float4 r;
        r.x = LRELU?lrelu_f(acc[py][q][j4*4+0]):acc[py][q][j4*4+0];
        r.y = LRELU?lrelu_f(acc[py][q][j4*4+1]):acc[py][q][j4*4+1];
        r.z = LRELU?lrelu_f(acc[py][q][j4*4+2]):acc[py][q][j4*4+2];
        r.w = LRELU?lrelu_f(acc[py][q][j4*4+3]):acc[py][q][j4*4+3];
        *(float4*)(op+j4*4) = r;
      }
    }
  }
}

// ============ dec4: s1 deconv == 3x3 pad-1 conv, Cout=1 — LDS-tiled ============
template<int H,int W,int CIN>
__global__ __launch_bounds__(256) void dec4_tiled_k(const float* __restrict__ in,
    const float* __restrict__ w, const float* __restrict__ bias, float* __restrict__ out){
  constexpr int TX=4, WB=128, TYB=8, GX=W/WB, GY=H/TYB, COLS=WB+2, ROWS=TYB+2;
  constexpr int NPIX = ROWS*COLS;                 // 1300 float4 slots per plane
  __shared__ float4 tile[2*NPIX];                 // plane0: ch c0..c0+3, plane1: c0+4..c0+7
  __shared__ float4 wsh[(9*CIN)/4];               // full 3x3xCIN weight (1.15 KB)

  int lb = swz_bid();
  int gx = lb % GX; int rest = lb / GX;
  int yg = rest % GY; int n = rest / GY;
  int xb = threadIdx.x & 31, yr = threadIdx.x >> 5;
  int y0 = yg*TYB, xbase = gx*WB;

  if (threadIdx.x < (9*CIN)/4) wsh[threadIdx.x] = ((const float4*)w)[threadIdx.x];

  float b0 = bias[0];
  float acc[TX];
  #pragma unroll
  for (int px=0;px<TX;px++) acc[px] = b0;

  for (int cc=0; cc<CIN/8; ++cc){
    __syncthreads();                               // prev reads done before overwrite
    for (int i = threadIdx.x; i < NPIX; i += 256){
      int row = i / COLS, col = i % COLS;
      int grow = y0 - 1 + row, gcol = xbase - 1 + col;
      float4 a0 = zero4(), a1 = zero4();
      if ((unsigned)grow < (unsigned)H && (unsigned)gcol < (unsigned)W){
        const float* gp = in + (((size_t)n*H + grow)*(size_t)W + gcol)*CIN + cc*8;
        a0 = *(const float4*)gp; a1 = *(const float4*)(gp + 4);
      }
      int p = row*COLS + (col ^ ((col>>2)&7));
      tile[p] = a0; tile[NPIX + p] = a1;
    }
    __syncthreads();

    #pragma unroll
    for (int ky=0;ky<3;ky++){
      int rowb = (yr + ky)*COLS;
      float4 w0[3], w1[3];
      #pragma unroll
      for (int kx=0;kx<3;kx++){
        int tf = (ky*3+kx)*(CIN/4) + cc*2;
        w0[kx] = wsh[tf]; w1[kx] = wsh[tf+1];
      }
      #pragma unroll
      for (int j=0;j<TX+2;j++){
        int col = 4*xb + j;
        int p = rowb + (col ^ ((col>>2)&7));
        float4 a0 = tile[p], a1 = tile[NPIX + p];
        #pragma unroll
        for (int kx=0;kx<3;kx++){
          int px = j - kx;
          if (px >= 0 && px < TX){
            acc[px] += a0.x*w0[kx].x + a0.y*w0[kx].y + a0.z*w0[kx].z + a0.w*w0[kx].w
                     + a1.x*w1[kx].x + a1.y*w1[kx].y + a1.z*w1[kx].z + a1.w*w1[kx].w;
          }
        }
      }
    }
  }

  int y = y0 + yr;
  float* op = out + ((size_t)n*H + y)*(size_t)W + xbase + 4*xb;
  float4 r; r.x=acc[0]; r.y=acc[1]; r.z=acc[2]; r.w=acc[3];
  *(float4*)op = r;
}

extern "C" void kernel_launch(void* const* d_in, const int* in_sizes, int n_in,
                              void* d_out, int out_size, void* d_ws, size_t ws_size,
                              hipStream_t stream) {
  const float* x   = (const float*)d_in[0];
  const float* e1w = (const float*)d_in[1];  const float* e1b = (const float*)d_in[2];
  const float* e2w = (const float*)d_in[3];  const float* e2b = (const float*)d_in[4];
  const float* e3w = (const float*)d_in[5];  const float* e3b = (const float*)d_in[6];
  const float* e4w = (const float*)d_in[7];  const float* e4b = (const float*)d_in[8];
  const float* cb  = (const float*)d_in[9];
  const float* d1w = (const float*)d_in[10]; const float* d1b = (const float*)d_in[11];
  const float* d2w = (const float*)d_in[12]; const float* d2b = (const float*)d_in[13];
  const float* d3w = (const float*)d_in[14]; const float* d3b = (const float*)d_in[15];
  const float* d4w = (const float*)d_in[16]; const float* d4b = (const float*)d_in[17];
  float* out = (float*)d_out;

  // Per-image ping-pong: A = max(h1,h3,d1,d3) = 8 MiB/img; B = max(h2,q,d2) = 4 MiB/img.
  const size_t MiB = 1ull << 20;
  int Bc = 32;
  while (Bc > 1 && (size_t)Bc * 12 * MiB > ws_size) Bc >>= 1;

  char* wsb = (char*)d_ws;
  float* A  = (float*)wsb;                              // Bc * 8 MiB
  float* Bf = (float*)(wsb + (size_t)Bc * 8 * MiB);     // Bc * 4 MiB

  for (int n0 = 0; n0 < 32; n0 += Bc) {
    const float* xc = x   + (size_t)n0 * 256*256*3;
    float*      oc  = out + (size_t)n0 * 256*256;

    // enc1: [Bc,256,256,3] -> [Bc,128,128,32]; TO=8(OB=4), TX=2(XB=64)
    int t1 = Bc*128*64*4;
    conv3x3_s2_k<256,256,3,32,8,2,true><<<t1/256,256,0,stream>>>(xc, e1w, e1b, A, t1);
    // enc2: -> [Bc,64,64,64]
    int t2 = Bc*64*32*8;
    conv3x3_s2_k<128,128,32,64,8,2,true><<<t2/256,256,0,stream>>>(A, e2w, e2b, Bf, t2);
    // enc3: -> [Bc,32,32,64]
    int t3 = Bc*32*16*8;
    conv3x3_s2_k<64,64,64,64,8,2,true><<<t3/256,256,0,stream>>>(Bf, e3w, e3b, A, t3);
    // enc4 (1x1, 64->32) + VQ: -> q [Bc,32,32,32]
    int npix = Bc*32*32;
    enc4_vq_k<64,32,64><<<npix/256,256,0,stream>>>(A, e4w, e4b, cb, Bf, npix);
    // dec1: [Bc,32,32,32] -> [Bc,64,64,64]; TO=8(OB=8), TX=2: XB2=16,TYR=16,YG=2 -> Bc*16
    deconv3x3_s2_fused_k<32,32,32,64,8,2,true><<<Bc*16,256,0,stream>>>(Bf, d1w, d1b, A);
    // dec2: -> [Bc,128,128,64]; TO=8(OB=8), TX=2: XB2=32,TYR=8,YG=8 -> Bc*64
    deconv3x3_s2_fused_k<64,64,64,64,8,2,true><<<Bc*64,256,0,stream>>>(A, d2w, d2b, Bf);
    // dec3: -> [Bc,256,256,32]; TO=8(OB=4), TX=2: XB2=64,TYR=4,YG=32 -> Bc*128
    deconv3x3_s2_fused_k<128,128,64,32,8,2,true><<<Bc*128,256,0,stream>>>(Bf, d3w, d3b, A);
    // dec4: -> [Bc,256,256,1]; LDS-tiled, grid = Bc*GX*GY = Bc*64
    dec4_tiled_k<256,256,32><<<Bc*64,256,0,stream>>>(A, d4w, d4b, oc);
  }
}

// Round 5
// 1059.284 us; speedup vs baseline: 1.5158x; 1.2997x over previous
//
#include <hip/hip_runtime.h>

#define ALPHA 0.2f
__device__ __forceinline__ float lrelu_f(float x){ return x>0.f ? x : ALPHA*x; }
__device__ __forceinline__ float4 zero4(){ float4 z; z.x=z.y=z.z=z.w=0.f; return z; }

// XCD-chunk swizzle: consecutive physical blocks land on the same XCD's contiguous
// logical chunk. Bijective iff grid%8==0; identity fallback otherwise.
__device__ __forceinline__ int swz_bid(){
  int nb = gridDim.x, b = blockIdx.x;
  return ((nb & 7)==0) ? ((b & 7)*(nb>>3) + (b>>3)) : b;
}

// ============ Encoder: 3x3 s2 SAME conv (pad lo=0,hi=1), NHWC in/out (unchanged) ============
template<int H,int W,int CIN,int COUT,int TO,int TX,bool LRELU>
__global__ __launch_bounds__(256) void conv3x3_s2_k(const float* __restrict__ in,
    const float* __restrict__ w, const float* __restrict__ bias, float* __restrict__ out,
    int total){
  constexpr int Ho=H/2, Wo=W/2, OB=COUT/TO, XB=Wo/TX;
  int t = swz_bid()*256 + threadIdx.x;
  if (t >= total) return;
  int ob = t % OB; int p = t/OB;
  int xb = p % XB; p /= XB;
  int y  = p % Ho; int n = p/Ho;
  int x0 = xb*TX;

  float acc[TX][TO];
  #pragma unroll
  for (int j4=0;j4<TO/4;j4++){
    float4 bv = *(const float4*)(bias + ob*TO + j4*4);
    #pragma unroll
    for (int px=0;px<TX;px++){
      acc[px][j4*4+0]=bv.x; acc[px][j4*4+1]=bv.y;
      acc[px][j4*4+2]=bv.z; acc[px][j4*4+3]=bv.w;
    }
  }

  #pragma unroll
  for (int ky=0;ky<3;ky++){
    int iy = 2*y + ky;
    if (iy >= H) continue;
    const float* row = in + ((size_t)n*H + iy)*(size_t)(W*CIN);
    #pragma unroll
    for (int kx=0;kx<3;kx++){
      const float* wp = w + ((ky*3+kx)*CIN)*COUT + ob*TO;
      const float* ipx[TX]; bool okx[TX];
      #pragma unroll
      for (int px=0;px<TX;px++){
        int ix = 2*(x0+px)+kx;
        okx[px] = (ix < W);
        ipx[px] = row + (size_t)(okx[px] ? ix : (W-1))*CIN;
      }
      if constexpr (CIN==3){
        #pragma unroll
        for (int ci=0;ci<3;ci++){
          float4 wv[TO/4];
          #pragma unroll
          for (int j4=0;j4<TO/4;j4++) wv[j4] = *(const float4*)(wp + ci*COUT + j4*4);
          #pragma unroll
          for (int px=0;px<TX;px++){
            float v = okx[px] ? ipx[px][ci] : 0.f;
            #pragma unroll
            for (int j4=0;j4<TO/4;j4++){
              acc[px][j4*4+0] += v*wv[j4].x; acc[px][j4*4+1] += v*wv[j4].y;
              acc[px][j4*4+2] += v*wv[j4].z; acc[px][j4*4+3] += v*wv[j4].w;
            }
          }
        }
      } else {
        for (int c=0;c<CIN;c+=4){
          float4 wv[4][TO/4];
          #pragma unroll
          for (int ci=0;ci<4;ci++)
            #pragma unroll
            for (int j4=0;j4<TO/4;j4++)
              wv[ci][j4] = *(const float4*)(wp + (c+ci)*COUT + j4*4);
          #pragma unroll
          for (int px=0;px<TX;px++){
            float4 vv = *(const float4*)(ipx[px]+c);
            if (!okx[px]) vv = zero4();
            float vc[4] = {vv.x, vv.y, vv.z, vv.w};
            #pragma unroll
            for (int ci=0;ci<4;ci++)
              #pragma unroll
              for (int j4=0;j4<TO/4;j4++){
                acc[px][j4*4+0] += vc[ci]*wv[ci][j4].x;
                acc[px][j4*4+1] += vc[ci]*wv[ci][j4].y;
                acc[px][j4*4+2] += vc[ci]*wv[ci][j4].z;
                acc[px][j4*4+3] += vc[ci]*wv[ci][j4].w;
              }
          }
        }
      }
    }
  }
  #pragma unroll
  for (int px=0;px<TX;px++){
    float* op = out + ((size_t)((n*Ho+y)*Wo + x0+px))*COUT + ob*TO;
    #pragma unroll
    for (int j4=0;j4<TO/4;j4++){
      float4 r;
      r.x = LRELU?lrelu_f(acc[px][j4*4+0]):acc[px][j4*4+0];
      r.y = LRELU?lrelu_f(acc[px][j4*4+1]):acc[px][j4*4+1];
      r.z = LRELU?lrelu_f(acc[px][j4*4+2]):acc[px][j4*4+2];
      r.w = LRELU?lrelu_f(acc[px][j4*4+3]):acc[px][j4*4+3];
      *(float4*)(op+j4*4) = r;
    }
  }
}

// ============ Fused enc4 (1x1 conv 64->32) + VQ; q written BLOCKED [N,D/4,H,W,4] ============
template<int CIN,int D,int K,int PIXI>   // PIXI = pixels per image (H*W)
__global__ __launch_bounds__(256) void enc4_vq_k(const float* __restrict__ in,
    const float* __restrict__ w, const float* __restrict__ bias,
    const float* __restrict__ cb, float* __restrict__ q, int npix){
  int i = blockIdx.x*256 + threadIdx.x;
  if (i >= npix) return;
  const float* ip = in + (size_t)i*CIN;
  float z[D];
  #pragma unroll
  for (int d=0; d<D; d++) z[d] = bias[d];
  for (int c=0; c<CIN; c+=4){
    float4 v = *(const float4*)(ip + c);
    #pragma unroll
    for (int d=0; d<D; d++){
      z[d] += v.x * w[(c+0)*D + d];
      z[d] += v.y * w[(c+1)*D + d];
      z[d] += v.z * w[(c+2)*D + d];
      z[d] += v.w * w[(c+3)*D + d];
    }
  }
  float z2 = 0.f;
  #pragma unroll
  for (int d=0; d<D; d++) z2 += z[d]*z[d];
  float best = 3.4e38f; int bi = 0;
  for (int k=0; k<K; k++){
    float e2 = 0.f, dot = 0.f;
    #pragma unroll
    for (int d=0; d<D; d++){
      float cv = cb[d*K + k];
      e2  += cv*cv;
      dot += z[d]*cv;
    }
    float dist = z2 + e2 - 2.f*dot;
    if (dist < best){ best = dist; bi = k; }   // strict < == first-min (jnp.argmin)
  }
  int n = i / PIXI, pix = i % PIXI;
  #pragma unroll
  for (int p=0; p<D/4; p++){
    float4 f;
    f.x = cb[(4*p+0)*K + bi]; f.y = cb[(4*p+1)*K + bi];
    f.z = cb[(4*p+2)*K + bi]; f.w = cb[(4*p+3)*K + bi];
    *(float4*)(q + ((size_t)(n*(D/4)+p)*PIXI + pix)*4) = f;   // coalesced per plane
  }
}

// ======== Parity-fused deconv 3x3 s2 SAME, BLOCKED [N,C/4,H,W,4] in AND out ========
// One thread: 2x2 parities x TX input-cols x TO chans. ob block-level; weights in LDS.
// Blocked layout -> input reads are 3 contiguous float4/row, 32-B lane stride (coalesced);
// stores are 64-B contiguous runs per plane.
template<int H,int W,int CIN,int COUT,int TO,int TX,bool LRELU>
__global__ __launch_bounds__(256) void deconv3x3_s2_blk_k(const float* __restrict__ in,
    const float* __restrict__ w, const float* __restrict__ bias, float* __restrict__ out){
  constexpr int Ho=2*H, Wo=2*W, OB=COUT/TO, XB2=W/TX, TYR=256/XB2, YG=H/TYR;
  constexpr int PI=CIN/4, PO=COUT/4;
  constexpr int WN = 9*CIN*TO;
  static_assert(256 % XB2 == 0 && H % TYR == 0, "geometry");
  __shared__ float wlds[WN];

  int lb = swz_bid();
  int ob = lb % OB; int g = lb / OB;
  int yg = g % YG;  int n  = g / YG;
  int xb = threadIdx.x % XB2, yr = threadIdx.x / XB2;
  int yy = yg*TYR + yr, x0 = xb*TX;

  // stage weight slice: w[(tap*CIN+c)*COUT + ob*TO + j] -> wlds[(tap*CIN+c)*TO + j]
  {
    const int base = ob*TO;
    for (int i = threadIdx.x; i < WN/4; i += 256){
      int j4 = i % (TO/4); int rest = i / (TO/4);          // rest = tap*CIN + c
      ((float4*)wlds)[i] = *(const float4*)(w + (size_t)rest*COUT + base + j4*4);
    }
  }
  __syncthreads();

  float acc[2][2*TX][TO];
  #pragma unroll
  for (int j4=0;j4<TO/4;j4++){
    float4 bv = *(const float4*)(bias + ob*TO + j4*4);
    #pragma unroll
    for (int py=0;py<2;py++)
      #pragma unroll
      for (int q=0;q<2*TX;q++){
        acc[py][q][j4*4+0]=bv.x; acc[py][q][j4*4+1]=bv.y;
        acc[py][q][j4*4+2]=bv.z; acc[py][q][j4*4+3]=bv.w;
      }
  }

  const bool has0 = (yy > 0);
  const float* nin = in + (size_t)n*PI*H*(size_t)(W*4);

  for (int pc=0; pc<PI; ++pc){
    const float* pbase = nin + (size_t)pc*H*(size_t)(W*4);
    const float* r1p = pbase + (size_t)yy*(W*4);
    const float* r0p = pbase + (size_t)(has0 ? yy-1 : 0)*(W*4);
    // ---- contiguous loads: cols x0-1 .. x0+TX-1, both rows ----
    float4 v0[TX+1], v1[TX+1];
    #pragma unroll
    for (int j=0;j<=TX;j++){
      int xi = x0 - 1 + j;
      bool ok = (xi >= 0);
      int off = (ok ? xi : 0)*4;
      float4 a1 = *(const float4*)(r1p + off);
      float4 a0 = has0 ? *(const float4*)(r0p + off) : zero4();
      if (!ok){ a1 = zero4(); a0 = zero4(); }
      v1[j] = a1; v0[j] = a0;
    }
    // ---- 9 taps ----
    const int c = pc*4;
    #pragma unroll
    for (int ky=0;ky<3;ky++){
      const int py = (ky==1) ? 1 : 0;
      #pragma unroll
      for (int kx=0;kx<3;kx++){
        const int pxp = (kx==1) ? 1 : 0;
        const float* wp = wlds + ((ky*3+kx)*CIN + c)*TO;   // LDS, wave-uniform
        float4 wv[4][TO/4];
        #pragma unroll
        for (int ci=0;ci<4;ci++)
          #pragma unroll
          for (int j4=0;j4<TO/4;j4++)
            wv[ci][j4] = *(const float4*)(wp + ci*TO + j4*4);
        #pragma unroll
        for (int px=0;px<TX;px++){
          const int jj = (kx==0) ? px : (px+1);   // dx=-1 -> col x0+px-1; dx=0 -> col x0+px
          float4 vv = (ky==0) ? v0[jj] : v1[jj];
          float vc[4] = {vv.x, vv.y, vv.z, vv.w};
          #pragma unroll
          for (int ci=0;ci<4;ci++)
            #pragma unroll
            for (int j4=0;j4<TO/4;j4++){
              acc[py][2*px+pxp][j4*4+0] += vc[ci]*wv[ci][j4].x;
              acc[py][2*px+pxp][j4*4+1] += vc[ci]*wv[ci][j4].y;
              acc[py][2*px+pxp][j4*4+2] += vc[ci]*wv[ci][j4].z;
              acc[py][2*px+pxp][j4*4+3] += vc[ci]*wv[ci][j4].w;
            }
        }
      }
    }
  }

  // ---- store: per parity-row, per out-plane (2 planes for TO=8), 2*TX contiguous packets
  float* nout = out + (size_t)n*PO*Ho*(size_t)(Wo*4);
  #pragma unroll
  for (int py=0;py<2;py++){
    int yo = 2*yy + py;
    #pragma unroll
    for (int h2=0; h2<TO/4; ++h2){
      int pp = ob*(TO/4) + h2;
      float* op = nout + ((size_t)pp*Ho + yo)*(size_t)(Wo*4) + (size_t)(2*x0)*4;
      #pragma unroll
      for (int q=0;q<2*TX;q++){
        float4 r;
        r.x = LRELU?lrelu_f(acc[py][q][h2*4+0]):acc[py][q][h2*4+0];
        r.y = LRELU?lrelu_f(acc[py][q][h2*4+1]):acc[py][q][h2*4+1];
        r.z = LRELU?lrelu_f(acc[py][q][h2*4+2]):acc[py][q][h2*4+2];
        r.w = LRELU?lrelu_f(acc[py][q][h2*4+3]):acc[py][q][h2*4+3];
        *(float4*)(op + q*4) = r;
      }
    }
  }
}

// ============ dec4: 3x3 pad-1 conv, Cout=1 — LDS-tiled, BLOCKED input ============
template<int H,int W,int CIN>
__global__ __launch_bounds__(256) void dec4_tiled_k(const float* __restrict__ in,
    const float* __restrict__ w, const float* __restrict__ bias, float* __restrict__ out){
  constexpr int TX=4, WB=128, TYB=8, GX=W/WB, GY=H/TYB, COLS=WB+2, ROWS=TYB+2;
  constexpr int NPIX = ROWS*COLS;                 // 1300 float4 slots per plane
  constexpr int PI = CIN/4;
  __shared__ float4 tile[2*NPIX];                 // plane pair per c-chunk
  __shared__ float4 wsh[(9*CIN)/4];               // full 3x3xCIN weight (1.15 KB)

  int lb = swz_bid();
  int gx = lb % GX; int rest = lb / GX;
  int yg = rest % GY; int n = rest / GY;
  int xb = threadIdx.x & 31, yr = threadIdx.x >> 5;
  int y0 = yg*TYB, xbase = gx*WB;

  if (threadIdx.x < (9*CIN)/4) wsh[threadIdx.x] = ((const float4*)w)[threadIdx.x];

  const float* nin = in + (size_t)n*PI*H*(size_t)(W*4);

  float b0 = bias[0];
  float acc[TX];
  #pragma unroll
  for (int px=0;px<TX;px++) acc[px] = b0;

  for (int cc=0; cc<CIN/8; ++cc){
    __syncthreads();                               // prev reads done before overwrite
    const float* p0 = nin + (size_t)(2*cc  )*H*(size_t)(W*4);
    const float* p1 = nin + (size_t)(2*cc+1)*H*(size_t)(W*4);
    for (int i = threadIdx.x; i < NPIX; i += 256){
      int row = i / COLS, col = i % COLS;
      int grow = y0 - 1 + row, gcol = xbase - 1 + col;
      float4 a0 = zero4(), a1 = zero4();
      if ((unsigned)grow < (unsigned)H && (unsigned)gcol < (unsigned)W){
        size_t off = (size_t)grow*(W*4) + (size_t)gcol*4;
        a0 = *(const float4*)(p0 + off); a1 = *(const float4*)(p1 + off);
      }
      int p = row*COLS + (col ^ ((col>>2)&7));
      tile[p] = a0; tile[NPIX + p] = a1;
    }
    __syncthreads();

    #pragma unroll
    for (int ky=0;ky<3;ky++){
      int rowb = (yr + ky)*COLS;
      float4 w0[3], w1[3];
      #pragma unroll
      for (int kx=0;kx<3;kx++){
        int tf = (ky*3+kx)*(CIN/4) + cc*2;
        w0[kx] = wsh[tf]; w1[kx] = wsh[tf+1];
      }
      #pragma unroll
      for (int j=0;j<TX+2;j++){
        int col = 4*xb + j;
        int p = rowb + (col ^ ((col>>2)&7));
        float4 a0 = tile[p], a1 = tile[NPIX + p];
        #pragma unroll
        for (int kx=0;kx<3;kx++){
          int px = j - kx;
          if (px >= 0 && px < TX){
            acc[px] += a0.x*w0[kx].x + a0.y*w0[kx].y + a0.z*w0[kx].z + a0.w*w0[kx].w
                     + a1.x*w1[kx].x + a1.y*w1[kx].y + a1.z*w1[kx].z + a1.w*w1[kx].w;
          }
        }
      }
    }
  }

  int y = y0 + yr;
  float* op = out + ((size_t)n*H + y)*(size_t)W + xbase + 4*xb;
  float4 r; r.x=acc[0]; r.y=acc[1]; r.z=acc[2]; r.w=acc[3];
  *(float4*)op = r;
}

extern "C" void kernel_launch(void* const* d_in, const int* in_sizes, int n_in,
                              void* d_out, int out_size, void* d_ws, size_t ws_size,
                              hipStream_t stream) {
  const float* x   = (const float*)d_in[0];
  const float* e1w = (const float*)d_in[1];  const float* e1b = (const float*)d_in[2];
  const float* e2w = (const float*)d_in[3];  const float* e2b = (const float*)d_in[4];
  const float* e3w = (const float*)d_in[5];  const float* e3b = (const float*)d_in[6];
  const float* e4w = (const float*)d_in[7];  const float* e4b = (const float*)d_in[8];
  const float* cb  = (const float*)d_in[9];
  const float* d1w = (const float*)d_in[10]; const float* d1b = (const float*)d_in[11];
  const float* d2w = (const float*)d_in[12]; const float* d2b = (const float*)d_in[13];
  const float* d3w = (const float*)d_in[14]; const float* d3b = (const float*)d_in[15];
  const float* d4w = (const float*)d_in[16]; const float* d4b = (const float*)d_in[17];
  float* out = (float*)d_out;

  // Per-image ping-pong: A = max(h1,h3,d1,d3) = 8 MiB/img; B = max(h2,q,d2) = 4 MiB/img.
  const size_t MiB = 1ull << 20;
  int Bc = 32;
  while (Bc > 1 && (size_t)Bc * 12 * MiB > ws_size) Bc >>= 1;

  char* wsb = (char*)d_ws;
  float* A  = (float*)wsb;                              // Bc * 8 MiB
  float* Bf = (float*)(wsb + (size_t)Bc * 8 * MiB);     // Bc * 4 MiB

  for (int n0 = 0; n0 < 32; n0 += Bc) {
    const float* xc = x   + (size_t)n0 * 256*256*3;
    float*      oc  = out + (size_t)n0 * 256*256;

    // enc1: [Bc,256,256,3] -> [Bc,128,128,32] NHWC
    int t1 = Bc*128*64*4;
    conv3x3_s2_k<256,256,3,32,8,2,true><<<t1/256,256,0,stream>>>(xc, e1w, e1b, A, t1);
    // enc2: -> [Bc,64,64,64] NHWC
    int t2 = Bc*64*32*8;
    conv3x3_s2_k<128,128,32,64,8,2,true><<<t2/256,256,0,stream>>>(A, e2w, e2b, Bf, t2);
    // enc3: -> [Bc,32,32,64] NHWC
    int t3 = Bc*32*16*8;
    conv3x3_s2_k<64,64,64,64,8,2,true><<<t3/256,256,0,stream>>>(Bf, e3w, e3b, A, t3);
    // enc4 (1x1, 64->32) + VQ: -> q [Bc,8,32,32,4] BLOCKED
    int npix = Bc*32*32;
    enc4_vq_k<64,32,64,1024><<<npix/256,256,0,stream>>>(A, e4w, e4b, cb, Bf, npix);
    // dec1: q -> d1 [Bc,16,64,64,4]; XB2=16,TYR=16,YG=2,OB=8 -> Bc*16
    deconv3x3_s2_blk_k<32,32,32,64,8,2,true><<<Bc*16,256,0,stream>>>(Bf, d1w, d1b, A);
    // dec2: -> d2 [Bc,16,128,128,4]; XB2=32,TYR=8,YG=8,OB=8 -> Bc*64
    deconv3x3_s2_blk_k<64,64,64,64,8,2,true><<<Bc*64,256,0,stream>>>(A, d2w, d2b, Bf);
    // dec3: -> d3 [Bc,8,256,256,4]; XB2=64,TYR=4,YG=32,OB=4 -> Bc*128
    deconv3x3_s2_blk_k<128,128,64,32,8,2,true><<<Bc*128,256,0,stream>>>(Bf, d3w, d3b, A);
    // dec4: d3 BLOCKED -> [Bc,256,256,1]; LDS-tiled, grid = Bc*64
    dec4_tiled_k<256,256,32><<<Bc*64,256,0,stream>>>(A, d4w, d4b, oc);
  }
}